// Round 8
// baseline (20026.074 us; speedup 1.0000x reference)
//
#include <hip/hip_runtime.h>
#include <hip/hip_bf16.h>

#define NROWS 16384
#define XD 1024
#define DD 4096

typedef __attribute__((ext_vector_type(8))) short short8;
typedef __attribute__((ext_vector_type(4))) float f32x4;

__device__ __forceinline__ unsigned short f2bf(float f) {
  unsigned int u = __builtin_bit_cast(unsigned int, f);
  u += 0x7fffu + ((u >> 16) & 1u);
  return (unsigned short)(u >> 16);
}

__device__ __forceinline__ void load_lds16(const void* g, void* l) {
  __builtin_amdgcn_global_load_lds((const __attribute__((address_space(1))) void*)g,
                                   (__attribute__((address_space(3))) void*)l, 16, 0, 0);
}

// ---------------- row mask ----------------
__global__ __launch_bounds__(256) void mask_kernel(const float* __restrict__ u,
                                                   const float* __restrict__ v,
                                                   float* __restrict__ w) {
  int r = blockIdx.x;
  int t = threadIdx.x;
  const f32x4* up = (const f32x4*)(u + (size_t)r * XD);
  const f32x4* vp = (const f32x4*)(v + (size_t)r * DD);
  f32x4 a = up[t];
  int fu = __syncthreads_or((a.x != 0.f) | (a.y != 0.f) | (a.z != 0.f) | (a.w != 0.f));
  int fv = 0;
#pragma unroll
  for (int it = 0; it < DD / (256 * 4); ++it) {
    if (!fv) {
      f32x4 b = vp[it * 256 + t];
      fv = __syncthreads_or((b.x != 0.f) | (b.y != 0.f) | (b.z != 0.f) | (b.w != 0.f));
    }
  }
  if (t == 0) w[r] = (fu && fv) ? 1.f : 0.f;
}

// ---------------- k = sum(w) ----------------
__global__ __launch_bounds__(256) void ksum_kernel(const float* __restrict__ w,
                                                   float* __restrict__ kout) {
  __shared__ float sm[256];
  float s = 0.f;
  for (int i = threadIdx.x; i < NROWS; i += 256) s += w[i];
  sm[threadIdx.x] = s;
  __syncthreads();
  for (int st = 128; st > 0; st >>= 1) {
    if (threadIdx.x < st) sm[threadIdx.x] += sm[threadIdx.x + st];
    __syncthreads();
  }
  if (threadIdx.x == 0) kout[0] = sm[0];
}

// ---------------- column stats ----------------
__global__ __launch_bounds__(256) void colstats_partial(const float* __restrict__ X, int cols,
                                                        const float* __restrict__ w,
                                                        float* __restrict__ p1,
                                                        float* __restrict__ p2) {
  int c = blockIdx.x * 256 + threadIdx.x;
  int r0 = blockIdx.y * (NROWS / 64);
  float s1 = 0.f, s2 = 0.f;
  for (int r = r0; r < r0 + NROWS / 64; ++r) {
    float wr = w[r];
    float x = X[(size_t)r * cols + c];
    float xw = x * wr;
    s1 += xw;
    s2 += xw * x;
  }
  p1[(size_t)blockIdx.y * cols + c] = s1;
  p2[(size_t)blockIdx.y * cols + c] = s2;
}

__global__ __launch_bounds__(256) void colstats_final(const float* __restrict__ p1,
                                                      const float* __restrict__ p2,
                                                      const float* __restrict__ kptr, int cols,
                                                      float* __restrict__ mean,
                                                      float* __restrict__ inv) {
  int c = blockIdx.x * 256 + threadIdx.x;
  float s1 = 0.f, s2 = 0.f;
  for (int j = 0; j < 64; ++j) {
    s1 += p1[(size_t)j * cols + c];
    s2 += p2[(size_t)j * cols + c];
  }
  float k = kptr[0];
  float m = s1 / k;
  float s = s2 - s1 * s1 / k;
  float sd = sqrtf(fmaxf(s, 0.f) / (k - 1.f));
  mean[c] = m;
  inv[c] = 1.f / (sd + 1e-7f);
}

// ---------------- weight transpose+convert: W[R][C] f32 -> T[C][R] bf16 ----------------
__global__ __launch_bounds__(256) void wt_kernel(const float* __restrict__ W, int R, int C,
                                                 unsigned short* __restrict__ T) {
  __shared__ unsigned short tile[64][65];
  int r0 = blockIdx.x * 64, c0 = blockIdx.y * 64;
  int tr = threadIdx.x >> 2;
  int tc = (threadIdx.x & 3) * 16;
  const float* src = W + (size_t)(r0 + tr) * C + c0 + tc;
#pragma unroll
  for (int i = 0; i < 16; i += 4) {
    f32x4 v4 = *(const f32x4*)(src + i);
    tile[tr][tc + i + 0] = f2bf(v4.x);
    tile[tr][tc + i + 1] = f2bf(v4.y);
    tile[tr][tc + i + 2] = f2bf(v4.z);
    tile[tr][tc + i + 3] = f2bf(v4.w);
  }
  __syncthreads();
  unsigned short* dst = T + (size_t)(c0 + tr) * R + r0 + tc;
  short8 o0, o1;
#pragma unroll
  for (int i = 0; i < 8; ++i) o0[i] = (short)tile[tc + i][tr];
#pragma unroll
  for (int i = 0; i < 8; ++i) o1[i] = (short)tile[tc + 8 + i][tr];
  *(short8*)(dst) = o0;
  *(short8*)(dst + 8) = o1;
}

// ---------------- normalize chunk: bf16 out ----------------
__global__ __launch_bounds__(256) void norm_kernel(const float* __restrict__ X,
                                                   const float* __restrict__ mean,
                                                   const float* __restrict__ inv,
                                                   unsigned short* __restrict__ O,
                                                   int colmask, size_t n8) {
  size_t stride = (size_t)gridDim.x * 256;
  for (size_t i = (size_t)blockIdx.x * 256 + threadIdx.x; i < n8; i += stride) {
    int c8 = (int)(i & (size_t)colmask);
    const float* xp = X + i * 8;
    f32x4 a = *(const f32x4*)xp;
    f32x4 b = *(const f32x4*)(xp + 4);
    f32x4 m0 = *(const f32x4*)(mean + c8 * 8);
    f32x4 m1 = *(const f32x4*)(mean + c8 * 8 + 4);
    f32x4 i0 = *(const f32x4*)(inv + c8 * 8);
    f32x4 i1 = *(const f32x4*)(inv + c8 * 8 + 4);
    short8 p;
    p[0] = (short)f2bf((a.x - m0.x) * i0.x);
    p[1] = (short)f2bf((a.y - m0.y) * i0.y);
    p[2] = (short)f2bf((a.z - m0.z) * i0.z);
    p[3] = (short)f2bf((a.w - m0.w) * i0.w);
    p[4] = (short)f2bf((b.x - m1.x) * i1.x);
    p[5] = (short)f2bf((b.y - m1.y) * i1.y);
    p[6] = (short)f2bf((b.z - m1.z) * i1.z);
    p[7] = (short)f2bf((b.w - m1.w) * i1.w);
    *(short8*)(O + i * 8) = p;
  }
}

// ---------------- 256x256 GEMM, BK=64, SINGLE 64KB buffer -> 2 blocks/CU ----------------
// C[M][N] = A[M][K] (bf16 k-contig) x Bt[N][K]^T (bf16 k-contig)
// Per tile: stage 8 loads -> vmcnt(0)+barrier -> interleaved frag-read/MFMA -> barrier.
// Stage-drain of one block is covered by the other resident block's MFMA phase (m114).
// Supertile block map for L2 sharing; XOR-swizzled LDS (conflict-free, rule 21).
// EPI 0: H = relu(C + bias) -> bf16 ;  EPI 1: O = (C + bias) * wrow -> f32
template <int EPI>
__global__ __launch_bounds__(512, 4) void gemm8p(const unsigned short* __restrict__ A,
                                                 const unsigned short* __restrict__ Bt,
                                                 const float* __restrict__ bias,
                                                 const float* __restrict__ wrow,
                                                 void* __restrict__ OutP,
                                                 int N, int K) {
  __shared__ char lds[65536];  // A: [256][64]bf16 @0, B: same @32768
  const int tid = threadIdx.x;
  const int lane = tid & 63;
  const int wave = tid >> 6;     // 0..7
  const int wr = wave >> 2;      // 0..1 (m half, 128 rows)
  const int wc = wave & 3;       // 0..3 (n quarter, 64 cols)

  const int gn = N >> 8;
  const int nwg = gridDim.x;
  const int gm = nwg / gn;
  const int bid = blockIdx.x;
  // XCD-contiguous reorder + 4m x 8n supertile (one XCD's 32 CUs share panels)
  const int sw = (nwg & 7) ? bid : ((bid & 7) * (nwg >> 3) + (bid >> 3));
  const int SW_W = (gn >= 8) ? 8 : gn;
  const int SW_H = 32 / SW_W;
  int mt, nt;
  if ((gn % SW_W) == 0 && (gm % SW_H) == 0) {
    const int stn = gn / SW_W;
    const int st = sw >> 5;
    const int wi = sw & 31;
    mt = (st / stn) * SW_H + wi / SW_W;
    nt = (st % stn) * SW_W + wi % SW_W;
  } else {
    mt = sw / gn;
    nt = sw % gn;
  }
  const int m0 = mt << 8;
  const int n0 = nt << 8;

  // staging: chunk ca = i*8+wave covers rows ca*8..ca*8+7; source col pre-swizzled
  const int srow = lane >> 3;
  const int scol = ((lane & 7) ^ srow) << 3;

  const int NT = K >> 6;
  f32x4 acc[8][4] = {};

  const int fr = lane & 15;             // row/col within fragment
  const int kbyte = (lane >> 4) << 4;   // k byte offset within 64B half

#define STAGE(T)                                                                     \
  {                                                                                  \
    const int k0_ = (T) << 6;                                                        \
    _Pragma("unroll") for (int i = 0; i < 4; ++i) {                                  \
      const int row_ = i * 64 + wave * 8 + srow;                                     \
      const int co_ = (i * 8 + wave) * 1024;                                         \
      load_lds16(A + (size_t)(m0 + row_) * K + k0_ + scol, lds + co_);               \
      load_lds16(Bt + (size_t)(n0 + row_) * K + k0_ + scol, lds + 32768 + co_);      \
    }                                                                                \
  }

#define RD_B(S)                                                                       \
  _Pragma("unroll") for (int g = 0; g < 4; ++g) {                                     \
    const int r = wc * 64 + g * 16 + fr;                                              \
    bfr[S][g] = *(const short8*)(Bb + r * 128 + (((S)*64 + kbyte) ^ ((r & 7) << 4))); \
  }

#define RD_A(DST, Q, S)                                                             \
  _Pragma("unroll") for (int f = 0; f < 2; ++f) {                                   \
    const int r = wr * 128 + (Q)*32 + f * 16 + fr;                                  \
    DST[f] = *(const short8*)(Ab + r * 128 + (((S)*64 + kbyte) ^ ((r & 7) << 4)));  \
  }

#define MM(Q, S, SRC)                                                               \
  __builtin_amdgcn_s_setprio(1);                                                    \
  _Pragma("unroll") for (int f = 0; f < 2; ++f)                                     \
      _Pragma("unroll") for (int g = 0; g < 4; ++g)                                 \
          acc[(Q)*2 + f][g] = __builtin_amdgcn_mfma_f32_16x16x32_bf16(              \
              SRC[f], bfr[S][g], acc[(Q)*2 + f][g], 0, 0, 0);                       \
  __builtin_amdgcn_s_setprio(0);

  const char* const Ab = lds;
  const char* const Bb = lds + 32768;
  short8 bfr[2][4], aX[2], aY[2];

  for (int t = 0; t < NT; ++t) {
    STAGE(t);
    asm volatile("s_waitcnt vmcnt(0)" ::: "memory");
    __builtin_amdgcn_sched_barrier(0);
    __builtin_amdgcn_s_barrier();

    RD_B(0);
    RD_A(aX, 0, 0);
    RD_B(1);
    RD_A(aY, 0, 1);
    MM(0, 0, aX);
    RD_A(aX, 1, 0); MM(0, 1, aY);
    RD_A(aY, 1, 1); MM(1, 0, aX);
    RD_A(aX, 2, 0); MM(1, 1, aY);
    RD_A(aY, 2, 1); MM(2, 0, aX);
    RD_A(aX, 3, 0); MM(2, 1, aY);
    RD_A(aY, 3, 1); MM(3, 0, aX);
    MM(3, 1, aY);
    asm volatile("s_waitcnt lgkmcnt(0)" ::: "memory");
    __builtin_amdgcn_sched_barrier(0);
    __builtin_amdgcn_s_barrier();
  }
#undef STAGE
#undef RD_B
#undef RD_A
#undef MM

  const int colloc = wc * 64 + fr;
  const int rowb = wr * 128 + ((lane >> 4) << 2);
  if (EPI == 0) {
    unsigned short* H = (unsigned short*)OutP;
#pragma unroll
    for (int f = 0; f < 8; ++f)
#pragma unroll
      for (int g = 0; g < 4; ++g) {
        const int c = n0 + colloc + g * 16;
        const float b = bias[c];
#pragma unroll
        for (int r = 0; r < 4; ++r) {
          const int row = m0 + rowb + f * 16 + r;
          H[(size_t)row * N + c] = f2bf(fmaxf(acc[f][g][r] + b, 0.f));
        }
      }
  } else {
    float* O = (float*)OutP;
#pragma unroll
    for (int f = 0; f < 8; ++f)
#pragma unroll
      for (int g = 0; g < 4; ++g) {
        const int c = n0 + colloc + g * 16;
        const float b = bias[c];
#pragma unroll
        for (int r = 0; r < 4; ++r) {
          const int row = m0 + rowb + f * 16 + r;
          O[(size_t)row * N + c] = (acc[f][g][r] + b) * wrow[row];
        }
      }
  }
}

extern "C" void kernel_launch(void* const* d_in, const int* in_sizes, int n_in,
                              void* d_out, int out_size, void* d_ws, size_t ws_size,
                              hipStream_t stream) {
  const float* u    = (const float*)d_in[0];
  const float* v    = (const float*)d_in[1];
  const float* u_W1 = (const float*)d_in[2];
  const float* u_b1 = (const float*)d_in[3];
  const float* u_W2 = (const float*)d_in[4];
  const float* u_b2 = (const float*)d_in[5];
  const float* v_W1 = (const float*)d_in[6];
  const float* v_b1 = (const float*)d_in[7];
  const float* v_W2 = (const float*)d_in[8];
  const float* v_b2 = (const float*)d_in[9];
  float* out1 = (float*)d_out;
  float* out2 = out1 + (size_t)NROWS * XD;

  float* wsf = (float*)d_ws;
  size_t off = 0;
  float* w_     = wsf + off; off += NROWS;
  float* kv     = wsf + off; off += 16;
  float* u_mean = wsf + off; off += XD;
  float* u_inv  = wsf + off; off += XD;
  float* v_mean = wsf + off; off += DD;
  float* v_inv  = wsf + off; off += DD;
  float* p1u    = wsf + off; off += 64 * XD;
  float* p2u    = wsf + off; off += 64 * XD;
  float* p1v    = wsf + off; off += 64 * DD;
  float* p2v    = wsf + off; off += 64 * DD;

  size_t boff = (off * 4 + 255) & ~(size_t)255;
  unsigned short* W1Tu = (unsigned short*)((char*)d_ws + boff); boff += (size_t)(2 * XD) * XD * 2;
  unsigned short* W2Tu = (unsigned short*)((char*)d_ws + boff); boff += (size_t)XD * (2 * XD) * 2;
  unsigned short* W1Tv = (unsigned short*)((char*)d_ws + boff); boff += (size_t)(2 * DD) * DD * 2;
  unsigned short* W2Tv = (unsigned short*)((char*)d_ws + boff); boff += (size_t)DD * (2 * DD) * 2;
  size_t fixedB = (boff + 255) & ~(size_t)255;

  // choose chunk sizes by fit + grid-utilization cost
  static const int chs[7] = {16384, 8192, 4096, 2048, 1024, 512, 256};
  int CHu = 256, CHv = 256;
  double best = 1e30;
  for (int a = 0; a < 7; ++a)
    for (int b = 0; b < 7; ++b) {
      int cu = chs[a], cv = chs[b];
      size_t need = fixedB + (size_t)cu * XD * 6 + (size_t)cv * DD * 6 + 1024;
      if (need > ws_size) continue;
      auto util = [](int nwg) { return nwg >= 512 ? 1.0 : nwg / 512.0; };
      double cost = 68.75 / util((cu >> 8) * 8) + 68.75 / util((cu >> 8) * 4) +
                    550.0 / util((cv >> 8) * 32) + 550.0 / util((cv >> 8) * 16);
      if (cost < best) { best = cost; CHu = cu; CHv = cv; }
    }

  size_t p = fixedB;
  unsigned short* unc  = (unsigned short*)((char*)d_ws + p); p += (size_t)CHu * XD * 2;
  unsigned short* uhid = (unsigned short*)((char*)d_ws + p); p += (size_t)CHu * (2 * XD) * 2;
  unsigned short* vnc  = (unsigned short*)((char*)d_ws + p); p += (size_t)CHv * DD * 2;
  unsigned short* vhid = (unsigned short*)((char*)d_ws + p);

  // ---- stats ----
  mask_kernel<<<NROWS, 256, 0, stream>>>(u, v, w_);
  ksum_kernel<<<1, 256, 0, stream>>>(w_, kv);
  colstats_partial<<<dim3(XD / 256, 64), 256, 0, stream>>>(u, XD, w_, p1u, p2u);
  colstats_partial<<<dim3(DD / 256, 64), 256, 0, stream>>>(v, DD, w_, p1v, p2v);
  colstats_final<<<XD / 256, 256, 0, stream>>>(p1u, p2u, kv, XD, u_mean, u_inv);
  colstats_final<<<DD / 256, 256, 0, stream>>>(p1v, p2v, kv, DD, v_mean, v_inv);

  // ---- weights -> bf16 transposed ----
  wt_kernel<<<dim3(XD / 64, (2 * XD) / 64), 256, 0, stream>>>(u_W1, XD, 2 * XD, W1Tu);
  wt_kernel<<<dim3((2 * XD) / 64, XD / 64), 256, 0, stream>>>(u_W2, 2 * XD, XD, W2Tu);
  wt_kernel<<<dim3(DD / 64, (2 * DD) / 64), 256, 0, stream>>>(v_W1, DD, 2 * DD, W1Tv);
  wt_kernel<<<dim3((2 * DD) / 64, DD / 64), 256, 0, stream>>>(v_W2, 2 * DD, DD, W2Tv);

  // ---- u path ----
  for (int r0 = 0; r0 < NROWS; r0 += CHu) {
    size_t n8 = (size_t)CHu * XD / 8;
    int ng = (int)(n8 / 256 < 2048 ? n8 / 256 : 2048);
    norm_kernel<<<ng, 256, 0, stream>>>(u + (size_t)r0 * XD, u_mean, u_inv, unc, XD / 8 - 1, n8);
    gemm8p<0><<<(CHu >> 8) * ((2 * XD) >> 8), 512, 0, stream>>>(unc, W1Tu, u_b1, nullptr, uhid,
                                                                2 * XD, XD);
    gemm8p<1><<<(CHu >> 8) * (XD >> 8), 512, 0, stream>>>(uhid, W2Tu, u_b2, w_ + r0,
                                                          out1 + (size_t)r0 * XD, XD, 2 * XD);
  }
  // ---- v path ----
  for (int r0 = 0; r0 < NROWS; r0 += CHv) {
    size_t n8 = (size_t)CHv * DD / 8;
    int ng = (int)(n8 / 256 < 2048 ? n8 / 256 : 2048);
    norm_kernel<<<ng, 256, 0, stream>>>(v + (size_t)r0 * DD, v_mean, v_inv, vnc, DD / 8 - 1, n8);
    gemm8p<0><<<(CHv >> 8) * ((2 * DD) >> 8), 512, 0, stream>>>(vnc, W1Tv, v_b1, nullptr, vhid,
                                                                2 * DD, DD);
    gemm8p<1><<<(CHv >> 8) * (DD >> 8), 512, 0, stream>>>(vhid, W2Tv, v_b2, w_ + r0,
                                                          out2 + (size_t)r0 * DD, DD, 2 * DD);
  }
}

// Round 9
// 2268.594 us; speedup vs baseline: 8.8275x; 8.8275x over previous
//
#include <hip/hip_runtime.h>
#include <hip/hip_bf16.h>

#define NROWS 16384
#define XD 1024
#define DD 4096

typedef __attribute__((ext_vector_type(8))) short short8;
typedef __attribute__((ext_vector_type(4))) float f32x4;

__device__ __forceinline__ unsigned short f2bf(float f) {
  unsigned int u = __builtin_bit_cast(unsigned int, f);
  u += 0x7fffu + ((u >> 16) & 1u);
  return (unsigned short)(u >> 16);
}

__device__ __forceinline__ void load_lds16(const void* g, void* l) {
  __builtin_amdgcn_global_load_lds((const __attribute__((address_space(1))) void*)g,
                                   (__attribute__((address_space(3))) void*)l, 16, 0, 0);
}

// ---------------- row mask ----------------
__global__ __launch_bounds__(256) void mask_kernel(const float* __restrict__ u,
                                                   const float* __restrict__ v,
                                                   float* __restrict__ w) {
  int r = blockIdx.x;
  int t = threadIdx.x;
  const f32x4* up = (const f32x4*)(u + (size_t)r * XD);
  const f32x4* vp = (const f32x4*)(v + (size_t)r * DD);
  f32x4 a = up[t];
  int fu = __syncthreads_or((a.x != 0.f) | (a.y != 0.f) | (a.z != 0.f) | (a.w != 0.f));
  int fv = 0;
#pragma unroll
  for (int it = 0; it < DD / (256 * 4); ++it) {
    if (!fv) {
      f32x4 b = vp[it * 256 + t];
      fv = __syncthreads_or((b.x != 0.f) | (b.y != 0.f) | (b.z != 0.f) | (b.w != 0.f));
    }
  }
  if (t == 0) w[r] = (fu && fv) ? 1.f : 0.f;
}

// ---------------- k = sum(w) ----------------
__global__ __launch_bounds__(256) void ksum_kernel(const float* __restrict__ w,
                                                   float* __restrict__ kout) {
  __shared__ float sm[256];
  float s = 0.f;
  for (int i = threadIdx.x; i < NROWS; i += 256) s += w[i];
  sm[threadIdx.x] = s;
  __syncthreads();
  for (int st = 128; st > 0; st >>= 1) {
    if (threadIdx.x < st) sm[threadIdx.x] += sm[threadIdx.x + st];
    __syncthreads();
  }
  if (threadIdx.x == 0) kout[0] = sm[0];
}

// ---------------- column stats ----------------
__global__ __launch_bounds__(256) void colstats_partial(const float* __restrict__ X, int cols,
                                                        const float* __restrict__ w,
                                                        float* __restrict__ p1,
                                                        float* __restrict__ p2) {
  int c = blockIdx.x * 256 + threadIdx.x;
  int r0 = blockIdx.y * (NROWS / 64);
  float s1 = 0.f, s2 = 0.f;
  for (int r = r0; r < r0 + NROWS / 64; ++r) {
    float wr = w[r];
    float x = X[(size_t)r * cols + c];
    float xw = x * wr;
    s1 += xw;
    s2 += xw * x;
  }
  p1[(size_t)blockIdx.y * cols + c] = s1;
  p2[(size_t)blockIdx.y * cols + c] = s2;
}

__global__ __launch_bounds__(256) void colstats_final(const float* __restrict__ p1,
                                                      const float* __restrict__ p2,
                                                      const float* __restrict__ kptr, int cols,
                                                      float* __restrict__ mean,
                                                      float* __restrict__ inv) {
  int c = blockIdx.x * 256 + threadIdx.x;
  float s1 = 0.f, s2 = 0.f;
  for (int j = 0; j < 64; ++j) {
    s1 += p1[(size_t)j * cols + c];
    s2 += p2[(size_t)j * cols + c];
  }
  float k = kptr[0];
  float m = s1 / k;
  float s = s2 - s1 * s1 / k;
  float sd = sqrtf(fmaxf(s, 0.f) / (k - 1.f));
  mean[c] = m;
  inv[c] = 1.f / (sd + 1e-7f);
}

// ---------------- weight transpose+convert: W[R][C] f32 -> T[C][R] bf16 ----------------
__global__ __launch_bounds__(256) void wt_kernel(const float* __restrict__ W, int R, int C,
                                                 unsigned short* __restrict__ T) {
  __shared__ unsigned short tile[64][65];
  int r0 = blockIdx.x * 64, c0 = blockIdx.y * 64;
  int tr = threadIdx.x >> 2;
  int tc = (threadIdx.x & 3) * 16;
  const float* src = W + (size_t)(r0 + tr) * C + c0 + tc;
#pragma unroll
  for (int i = 0; i < 16; i += 4) {
    f32x4 v4 = *(const f32x4*)(src + i);
    tile[tr][tc + i + 0] = f2bf(v4.x);
    tile[tr][tc + i + 1] = f2bf(v4.y);
    tile[tr][tc + i + 2] = f2bf(v4.z);
    tile[tr][tc + i + 3] = f2bf(v4.w);
  }
  __syncthreads();
  unsigned short* dst = T + (size_t)(c0 + tr) * R + r0 + tc;
  short8 o0, o1;
#pragma unroll
  for (int i = 0; i < 8; ++i) o0[i] = (short)tile[tc + i][tr];
#pragma unroll
  for (int i = 0; i < 8; ++i) o1[i] = (short)tile[tc + 8 + i][tr];
  *(short8*)(dst) = o0;
  *(short8*)(dst + 8) = o1;
}

// ---------------- normalize chunk: bf16 out ----------------
__global__ __launch_bounds__(256) void norm_kernel(const float* __restrict__ X,
                                                   const float* __restrict__ mean,
                                                   const float* __restrict__ inv,
                                                   unsigned short* __restrict__ O,
                                                   int colmask, size_t n8) {
  size_t stride = (size_t)gridDim.x * 256;
  for (size_t i = (size_t)blockIdx.x * 256 + threadIdx.x; i < n8; i += stride) {
    int c8 = (int)(i & (size_t)colmask);
    const float* xp = X + i * 8;
    f32x4 a = *(const f32x4*)xp;
    f32x4 b = *(const f32x4*)(xp + 4);
    f32x4 m0 = *(const f32x4*)(mean + c8 * 8);
    f32x4 m1 = *(const f32x4*)(mean + c8 * 8 + 4);
    f32x4 i0 = *(const f32x4*)(inv + c8 * 8);
    f32x4 i1 = *(const f32x4*)(inv + c8 * 8 + 4);
    short8 p;
    p[0] = (short)f2bf((a.x - m0.x) * i0.x);
    p[1] = (short)f2bf((a.y - m0.y) * i0.y);
    p[2] = (short)f2bf((a.z - m0.z) * i0.z);
    p[3] = (short)f2bf((a.w - m0.w) * i0.w);
    p[4] = (short)f2bf((b.x - m1.x) * i1.x);
    p[5] = (short)f2bf((b.y - m1.y) * i1.y);
    p[6] = (short)f2bf((b.z - m1.z) * i1.z);
    p[7] = (short)f2bf((b.w - m1.w) * i1.w);
    *(short8*)(O + i * 8) = p;
  }
}

// ---------------- 256x256 GEMM, BK=64, 16 waves (4/SIMD), dbuf LDS ----------------
// C[M][N] = A[M][K] (bf16 k-contig) x Bt[N][K]^T (bf16 k-contig)
// 1024 threads, wave grid 4x4, 64x64 out/wave -> acc[4][4]=64 AGPR, ~120 regs total
// (fits the 128 cap of launch_bounds(1024,4) -> 4 waves/SIMD for latency overlap).
// Tile-ahead STAGE into double buffer; 2 barriers/tile; swizzled LDS; supertile map.
// EPI 0: H = relu(C + bias) -> bf16 ;  EPI 1: O = (C + bias) * wrow -> f32
template <int EPI>
__global__ __launch_bounds__(1024, 4) void gemm8p(const unsigned short* __restrict__ A,
                                                  const unsigned short* __restrict__ Bt,
                                                  const float* __restrict__ bias,
                                                  const float* __restrict__ wrow,
                                                  void* __restrict__ OutP,
                                                  int N, int K) {
  __shared__ char lds[131072];  // buf b: A @ b*65536, B @ b*65536+32768 (each 32KB)
  const int tid = threadIdx.x;
  const int lane = tid & 63;
  const int wave = tid >> 6;   // 0..15
  const int wm = wave >> 2;    // 0..3 (m 64-row block)
  const int wn = wave & 3;     // 0..3 (n 64-col block)

  const int gn = N >> 8;
  const int nwg = gridDim.x;
  const int gm = nwg / gn;
  const int bid = blockIdx.x;
  // XCD-contiguous reorder + 4m x 8n supertile (one XCD's CUs share panels)
  const int sw = (nwg & 7) ? bid : ((bid & 7) * (nwg >> 3) + (bid >> 3));
  const int SW_W = (gn >= 8) ? 8 : gn;
  const int SW_H = 32 / SW_W;
  int mt, nt;
  if ((gn % SW_W) == 0 && (gm % SW_H) == 0) {
    const int stn = gn / SW_W;
    const int st = sw >> 5;
    const int wi = sw & 31;
    mt = (st / stn) * SW_H + wi / SW_W;
    nt = (st % stn) * SW_W + wi % SW_W;
  } else {
    mt = sw / gn;
    nt = sw % gn;
  }
  const int m0 = mt << 8;
  const int n0 = nt << 8;

  // staging (1024 threads): inst i covers rows (tid>>3)+128i, slot tid&7 (16B),
  // source col pre-swizzled so LDS dest stays linear (rule 21)
  const int srow = tid >> 3;                       // 0..127
  const int scol = (((tid & 7) ^ (srow & 7)) << 3);

  const int NT = K >> 6;
  f32x4 acc[4][4] = {};

  const int fr = lane & 15;            // row within fragment
  const int kbyte = (lane >> 4) << 4;  // k byte offset within 64B half

#define STAGE(T, BUF)                                                                   \
  {                                                                                     \
    const int k0_ = (T) << 6;                                                           \
    _Pragma("unroll") for (int i = 0; i < 2; ++i) {                                     \
      const int row_ = srow + i * 128;                                                  \
      load_lds16(A + (size_t)(m0 + row_) * K + k0_ + scol,                              \
                 lds + (BUF)*65536 + i * 16384 + tid * 16);                             \
      load_lds16(Bt + (size_t)(n0 + row_) * K + k0_ + scol,                             \
                 lds + (BUF)*65536 + 32768 + i * 16384 + tid * 16);                     \
    }                                                                                   \
  }

  STAGE(0, 0);
  __syncthreads();

  short8 af[4], bf_[4];
  for (int t = 0; t < NT; ++t) {
    const int buf = t & 1;
    const char* Ab = lds + buf * 65536;
    const char* Bb = lds + buf * 65536 + 32768;
    if (t + 1 < NT) STAGE(t + 1, buf ^ 1);

#pragma unroll
    for (int s = 0; s < 2; ++s) {
#pragma unroll
      for (int f = 0; f < 4; ++f) {
        const int r = wm * 64 + f * 16 + fr;
        af[f] = *(const short8*)(Ab + r * 128 + ((s * 64 + kbyte) ^ ((r & 7) << 4)));
      }
#pragma unroll
      for (int g = 0; g < 4; ++g) {
        const int r = wn * 64 + g * 16 + fr;
        bf_[g] = *(const short8*)(Bb + r * 128 + ((s * 64 + kbyte) ^ ((r & 7) << 4)));
      }
      __builtin_amdgcn_s_setprio(1);
#pragma unroll
      for (int f = 0; f < 4; ++f)
#pragma unroll
        for (int g = 0; g < 4; ++g)
          acc[f][g] = __builtin_amdgcn_mfma_f32_16x16x32_bf16(af[f], bf_[g], acc[f][g], 0, 0, 0);
      __builtin_amdgcn_s_setprio(0);
    }
    __syncthreads();
  }
#undef STAGE

  const int colloc = wn * 64 + fr;
  const int rowb = wm * 64 + ((lane >> 4) << 2);
  if (EPI == 0) {
    unsigned short* H = (unsigned short*)OutP;
#pragma unroll
    for (int f = 0; f < 4; ++f)
#pragma unroll
      for (int g = 0; g < 4; ++g) {
        const int c = n0 + colloc + g * 16;
        const float b = bias[c];
#pragma unroll
        for (int r = 0; r < 4; ++r) {
          const int row = m0 + rowb + f * 16 + r;
          H[(size_t)row * N + c] = f2bf(fmaxf(acc[f][g][r] + b, 0.f));
        }
      }
  } else {
    float* O = (float*)OutP;
#pragma unroll
    for (int f = 0; f < 4; ++f)
#pragma unroll
      for (int g = 0; g < 4; ++g) {
        const int c = n0 + colloc + g * 16;
        const float b = bias[c];
#pragma unroll
        for (int r = 0; r < 4; ++r) {
          const int row = m0 + rowb + f * 16 + r;
          O[(size_t)row * N + c] = (acc[f][g][r] + b) * wrow[row];
        }
      }
  }
}

extern "C" void kernel_launch(void* const* d_in, const int* in_sizes, int n_in,
                              void* d_out, int out_size, void* d_ws, size_t ws_size,
                              hipStream_t stream) {
  const float* u    = (const float*)d_in[0];
  const float* v    = (const float*)d_in[1];
  const float* u_W1 = (const float*)d_in[2];
  const float* u_b1 = (const float*)d_in[3];
  const float* u_W2 = (const float*)d_in[4];
  const float* u_b2 = (const float*)d_in[5];
  const float* v_W1 = (const float*)d_in[6];
  const float* v_b1 = (const float*)d_in[7];
  const float* v_W2 = (const float*)d_in[8];
  const float* v_b2 = (const float*)d_in[9];
  float* out1 = (float*)d_out;
  float* out2 = out1 + (size_t)NROWS * XD;

  float* wsf = (float*)d_ws;
  size_t off = 0;
  float* w_     = wsf + off; off += NROWS;
  float* kv     = wsf + off; off += 16;
  float* u_mean = wsf + off; off += XD;
  float* u_inv  = wsf + off; off += XD;
  float* v_mean = wsf + off; off += DD;
  float* v_inv  = wsf + off; off += DD;
  float* p1u    = wsf + off; off += 64 * XD;
  float* p2u    = wsf + off; off += 64 * XD;
  float* p1v    = wsf + off; off += 64 * DD;
  float* p2v    = wsf + off; off += 64 * DD;

  size_t boff = (off * 4 + 255) & ~(size_t)255;
  unsigned short* W1Tu = (unsigned short*)((char*)d_ws + boff); boff += (size_t)(2 * XD) * XD * 2;
  unsigned short* W2Tu = (unsigned short*)((char*)d_ws + boff); boff += (size_t)XD * (2 * XD) * 2;
  unsigned short* W1Tv = (unsigned short*)((char*)d_ws + boff); boff += (size_t)(2 * DD) * DD * 2;
  unsigned short* W2Tv = (unsigned short*)((char*)d_ws + boff); boff += (size_t)DD * (2 * DD) * 2;
  size_t fixedB = (boff + 255) & ~(size_t)255;

  // choose chunk sizes by fit + grid-utilization cost
  static const int chs[7] = {16384, 8192, 4096, 2048, 1024, 512, 256};
  int CHu = 256, CHv = 256;
  double best = 1e30;
  for (int a = 0; a < 7; ++a)
    for (int b = 0; b < 7; ++b) {
      int cu = chs[a], cv = chs[b];
      size_t need = fixedB + (size_t)cu * XD * 6 + (size_t)cv * DD * 6 + 1024;
      if (need > ws_size) continue;
      auto util = [](int nwg) { return nwg >= 256 ? 1.0 : nwg / 256.0; };
      double cost = 68.75 / util((cu >> 8) * 8) + 68.75 / util((cu >> 8) * 4) +
                    550.0 / util((cv >> 8) * 32) + 550.0 / util((cv >> 8) * 16);
      if (cost < best) { best = cost; CHu = cu; CHv = cv; }
    }

  size_t p = fixedB;
  unsigned short* unc  = (unsigned short*)((char*)d_ws + p); p += (size_t)CHu * XD * 2;
  unsigned short* uhid = (unsigned short*)((char*)d_ws + p); p += (size_t)CHu * (2 * XD) * 2;
  unsigned short* vnc  = (unsigned short*)((char*)d_ws + p); p += (size_t)CHv * DD * 2;
  unsigned short* vhid = (unsigned short*)((char*)d_ws + p);

  // ---- stats ----
  mask_kernel<<<NROWS, 256, 0, stream>>>(u, v, w_);
  ksum_kernel<<<1, 256, 0, stream>>>(w_, kv);
  colstats_partial<<<dim3(XD / 256, 64), 256, 0, stream>>>(u, XD, w_, p1u, p2u);
  colstats_partial<<<dim3(DD / 256, 64), 256, 0, stream>>>(v, DD, w_, p1v, p2v);
  colstats_final<<<XD / 256, 256, 0, stream>>>(p1u, p2u, kv, XD, u_mean, u_inv);
  colstats_final<<<DD / 256, 256, 0, stream>>>(p1v, p2v, kv, DD, v_mean, v_inv);

  // ---- weights -> bf16 transposed ----
  wt_kernel<<<dim3(XD / 64, (2 * XD) / 64), 256, 0, stream>>>(u_W1, XD, 2 * XD, W1Tu);
  wt_kernel<<<dim3((2 * XD) / 64, XD / 64), 256, 0, stream>>>(u_W2, 2 * XD, XD, W2Tu);
  wt_kernel<<<dim3(DD / 64, (2 * DD) / 64), 256, 0, stream>>>(v_W1, DD, 2 * DD, W1Tv);
  wt_kernel<<<dim3((2 * DD) / 64, DD / 64), 256, 0, stream>>>(v_W2, 2 * DD, DD, W2Tv);

  // ---- u path ----
  for (int r0 = 0; r0 < NROWS; r0 += CHu) {
    size_t n8 = (size_t)CHu * XD / 8;
    int ng = (int)(n8 / 256 < 2048 ? n8 / 256 : 2048);
    norm_kernel<<<ng, 256, 0, stream>>>(u + (size_t)r0 * XD, u_mean, u_inv, unc, XD / 8 - 1, n8);
    gemm8p<0><<<(CHu >> 8) * ((2 * XD) >> 8), 1024, 0, stream>>>(unc, W1Tu, u_b1, nullptr, uhid,
                                                                 2 * XD, XD);
    gemm8p<1><<<(CHu >> 8) * (XD >> 8), 1024, 0, stream>>>(uhid, W2Tu, u_b2, w_ + r0,
                                                           out1 + (size_t)r0 * XD, XD, 2 * XD);
  }
  // ---- v path ----
  for (int r0 = 0; r0 < NROWS; r0 += CHv) {
    size_t n8 = (size_t)CHv * DD / 8;
    int ng = (int)(n8 / 256 < 2048 ? n8 / 256 : 2048);
    norm_kernel<<<ng, 256, 0, stream>>>(v + (size_t)r0 * DD, v_mean, v_inv, vnc, DD / 8 - 1, n8);
    gemm8p<0><<<(CHv >> 8) * ((2 * DD) >> 8), 1024, 0, stream>>>(vnc, W1Tv, v_b1, nullptr, vhid,
                                                                 2 * DD, DD);
    gemm8p<1><<<(CHv >> 8) * (DD >> 8), 1024, 0, stream>>>(vhid, W2Tv, v_b2, w_ + r0,
                                                           out2 + (size_t)r0 * DD, DD, 2 * DD);
  }
}